// Round 1
// baseline (4315.945 us; speedup 1.0000x reference)
//
#include <hip/hip_runtime.h>

typedef _Float16 half8 __attribute__((ext_vector_type(8)));
typedef _Float16 half4 __attribute__((ext_vector_type(4)));
typedef float    f32x4 __attribute__((ext_vector_type(4)));

constexpr int Bt   = 256;   // batch
constexpr int Hd   = 1024;  // hidden
constexpr int G4   = 4096;  // 4*H
constexpr int Ts   = 128;   // time steps
constexpr int DOUT = 128;
constexpr int NWG  = 256;
constexpr int NTHR = 256;

// workspace layout (bytes)
constexpr size_t OFF_WSUM = 0;                                // [4096][1024] f16
constexpr size_t OFF_WIH  = OFF_WSUM + (size_t)G4 * Hd * 2;   // [4096][1024] f16
constexpr size_t OFF_WOUT = OFF_WIH  + (size_t)G4 * Hd * 2;   // [128][1024] f16
constexpr size_t OFF_X    = OFF_WOUT + (size_t)DOUT * Hd * 2; // [256][1024] f16
constexpr size_t OFF_BSUM = OFF_X    + (size_t)Bt * Hd * 2;   // [4096] f32
constexpr size_t OFF_BAR  = OFF_BSUM + (size_t)G4 * 4;        // 2 counters, separate lines
constexpr size_t OFF_SEQ  = OFF_BAR  + 512;                   // [128][256][1024] f16
constexpr size_t WS_NEED  = OFF_SEQ  + (size_t)Ts * Bt * Hd * 2;

__device__ __forceinline__ float fast_sig(float x) {
    return 1.f / (1.f + __expf(-x));
}
__device__ __forceinline__ float fast_tanh(float x) {
    float ax = fabsf(x);
    float e  = __expf(-2.f * ax);
    float t  = (1.f - e) / (1.f + e);
    return copysignf(t, x);
}

// ---------------- precompute: f16 casts, W_sum, b_sum, barrier init ----------------
__global__ void prep_kernel(const float* __restrict__ Wih, const float* __restrict__ Whh,
                            const float* __restrict__ bih, const float* __restrict__ bhh,
                            const float* __restrict__ x,   const float* __restrict__ Wout,
                            _Float16* __restrict__ wsum16, _Float16* __restrict__ wih16,
                            _Float16* __restrict__ wout16, _Float16* __restrict__ x16,
                            float* __restrict__ bsum, unsigned* __restrict__ bar) {
    const int i0     = blockIdx.x * blockDim.x + threadIdx.x;
    const int stride = gridDim.x * blockDim.x;

    // W_sum & W_ih (4M elements, as float4 chunks)
    for (int i = i0; i < G4 * Hd / 4; i += stride) {
        f32x4 a = ((const f32x4*)Wih)[i];
        f32x4 b = ((const f32x4*)Whh)[i];
        half4 hs, hi;
        #pragma unroll
        for (int j = 0; j < 4; ++j) {
            hs[j] = (_Float16)(a[j] + b[j]);
            hi[j] = (_Float16)a[j];
        }
        ((half4*)wsum16)[i] = hs;
        ((half4*)wih16)[i]  = hi;
    }
    for (int i = i0; i < DOUT * Hd / 4; i += stride) {
        f32x4 a = ((const f32x4*)Wout)[i];
        half4 h;
        #pragma unroll
        for (int j = 0; j < 4; ++j) h[j] = (_Float16)a[j];
        ((half4*)wout16)[i] = h;
    }
    for (int i = i0; i < Bt * Hd / 4; i += stride) {
        f32x4 a = ((const f32x4*)x)[i];
        half4 h;
        #pragma unroll
        for (int j = 0; j < 4; ++j) h[j] = (_Float16)a[j];
        ((half4*)x16)[i] = h;
    }
    for (int i = i0; i < G4; i += stride) bsum[i] = bih[i] + bhh[i];
    if (i0 == 0) { bar[0] = 0u; bar[64] = 0u; }
}

// ---------------- grid barrier (sense via generation counter) ----------------
__device__ __forceinline__ void gridbar(unsigned* bar, unsigned target) {
    __syncthreads();
    if (threadIdx.x == 0) {
        unsigned* cnt = bar;
        unsigned* gen = bar + 64;
        unsigned old = __hip_atomic_fetch_add(cnt, 1u, __ATOMIC_ACQ_REL, __HIP_MEMORY_SCOPE_AGENT);
        if (old == (unsigned)NWG - 1u) {
            __hip_atomic_store(cnt, 0u, __ATOMIC_RELAXED, __HIP_MEMORY_SCOPE_AGENT);
            __hip_atomic_fetch_add(gen, 1u, __ATOMIC_ACQ_REL, __HIP_MEMORY_SCOPE_AGENT);
        } else {
            while (__hip_atomic_load(gen, __ATOMIC_ACQUIRE, __HIP_MEMORY_SCOPE_AGENT) < target) {
                __builtin_amdgcn_s_sleep(1);
            }
        }
    }
    __syncthreads();
}

// ---------------- persistent LSTM kernel ----------------
// WG wid: bb = wid>>6 (batch block of 64), jb = wid&63 (j block of 16).
// Wave w handles M-tile (16 batch rows) x 4 gate N-tiles (i,f,g,o at cols g*H + jb*16).
__launch_bounds__(NTHR)
__global__ void lstm_kernel(const _Float16* __restrict__ wsum16,
                            const _Float16* __restrict__ wih16,
                            const _Float16* __restrict__ wout16,
                            const _Float16* __restrict__ x16,
                            const float* __restrict__ bsum,
                            const float* __restrict__ bout,
                            _Float16* __restrict__ seq,
                            float* __restrict__ out,
                            unsigned* __restrict__ bar) {
    const int wid = blockIdx.x;
    const int bb  = wid >> 6;
    const int jb  = wid & 63;
    const int w   = threadIdx.x >> 6;
    const int l   = threadIdx.x & 63;
    const int lr  = l & 15;   // A-row / B-col / D-col index
    const int lk  = l >> 4;   // k sub-block (8 elems each)

    const int m0 = bb * 64 + w * 16;  // batch row base for this wave
    const int j0 = jb * 16;

    // element offsets, invariant over t and k0
    const int aoff = (m0 + lr) * Hd + lk * 8;
    int boff[4];
    #pragma unroll
    for (int g = 0; g < 4; ++g) boff[g] = (g * Hd + j0 + lr) * Hd + lk * 8;

    float bias[4];
    #pragma unroll
    for (int g = 0; g < 4; ++g) bias[g] = bsum[g * Hd + j0 + lr];

    f32x4 c = {0.f, 0.f, 0.f, 0.f};

    #pragma unroll 1
    for (int t = 0; t < Ts; ++t) {
        const _Float16* Asrc = (t == 0) ? x16 : (seq + (size_t)(t - 1) * Bt * Hd);
        const _Float16* Bsrc = (t == 0) ? wih16 : wsum16;

        f32x4 acc0 = {0,0,0,0}, acc1 = {0,0,0,0}, acc2 = {0,0,0,0}, acc3 = {0,0,0,0};
        #pragma unroll 4
        for (int k0 = 0; k0 < Hd; k0 += 32) {
            half8 a  = *(const half8*)(Asrc + aoff + k0);
            half8 b0 = *(const half8*)(Bsrc + boff[0] + k0);
            half8 b1 = *(const half8*)(Bsrc + boff[1] + k0);
            half8 b2 = *(const half8*)(Bsrc + boff[2] + k0);
            half8 b3 = *(const half8*)(Bsrc + boff[3] + k0);
            acc0 = __builtin_amdgcn_mfma_f32_16x16x32_f16(a, b0, acc0, 0, 0, 0);
            acc1 = __builtin_amdgcn_mfma_f32_16x16x32_f16(a, b1, acc1, 0, 0, 0);
            acc2 = __builtin_amdgcn_mfma_f32_16x16x32_f16(a, b2, acc2, 0, 0, 0);
            acc3 = __builtin_amdgcn_mfma_f32_16x16x32_f16(a, b3, acc3, 0, 0, 0);
        }

        // cell update: D layout col=lr, row=lk*4+r  (batch = m0+lk*4+r, j = j0+lr)
        _Float16* hrow = seq + (size_t)t * Bt * Hd;
        #pragma unroll
        for (int r = 0; r < 4; ++r) {
            float ig = fast_sig(acc0[r] + bias[0]);
            float fg = fast_sig(acc1[r] + bias[1]);
            float gg = fast_tanh(acc2[r] + bias[2]);
            float og = fast_sig(acc3[r] + bias[3]);
            float cn = fg * c[r] + ig * gg;
            c[r] = cn;
            float hv = og * fast_tanh(cn);
            hrow[(m0 + lk * 4 + r) * Hd + j0 + lr] = (_Float16)hv;
        }

        gridbar(bar, (unsigned)(t + 1));
    }

    // ---------------- fused output projection ----------------
    // seq is exactly A[32768][1024] row-major (Mrow = t*256 + b).
    // out[b][t][d] = seq_row . W_out[d] + b_out[d]
    const int gw = wid * 4 + w;  // 0..1023
    #pragma unroll 1
    for (int mm = 0; mm < 2; ++mm) {
        const int mi = gw * 2 + mm;  // M-tile 0..2047
        const int arow = (mi * 16 + lr) * Hd + lk * 8;
        f32x4 oacc[8];
        #pragma unroll
        for (int ni = 0; ni < 8; ++ni) oacc[ni] = f32x4{0,0,0,0};

        #pragma unroll 2
        for (int k0 = 0; k0 < Hd; k0 += 32) {
            half8 a = *(const half8*)(seq + arow + k0);
            #pragma unroll
            for (int ni = 0; ni < 8; ++ni) {
                half8 bf = *(const half8*)(wout16 + (ni * 16 + lr) * Hd + lk * 8 + k0);
                oacc[ni] = __builtin_amdgcn_mfma_f32_16x16x32_f16(a, bf, oacc[ni], 0, 0, 0);
            }
        }
        #pragma unroll
        for (int ni = 0; ni < 8; ++ni) {
            const int d  = ni * 16 + lr;
            const float bo = bout[d];
            #pragma unroll
            for (int r = 0; r < 4; ++r) {
                const int Mrow = mi * 16 + lk * 4 + r;
                const int tt = Mrow >> 8;
                const int bi = Mrow & 255;
                out[(size_t)bi * (Ts * DOUT) + tt * DOUT + d] = oacc[ni][r] + bo;
            }
        }
    }
}

extern "C" void kernel_launch(void* const* d_in, const int* in_sizes, int n_in,
                              void* d_out, int out_size, void* d_ws, size_t ws_size,
                              hipStream_t stream) {
    const float* x    = (const float*)d_in[0];
    const float* Wih  = (const float*)d_in[1];
    const float* Whh  = (const float*)d_in[2];
    const float* bih  = (const float*)d_in[3];
    const float* bhh  = (const float*)d_in[4];
    const float* Wout = (const float*)d_in[5];
    const float* bout = (const float*)d_in[6];

    if (ws_size < WS_NEED) return;  // loud failure via poison if ws too small

    char* ws = (char*)d_ws;
    _Float16* wsum16 = (_Float16*)(ws + OFF_WSUM);
    _Float16* wih16  = (_Float16*)(ws + OFF_WIH);
    _Float16* wout16 = (_Float16*)(ws + OFF_WOUT);
    _Float16* x16    = (_Float16*)(ws + OFF_X);
    float*    bsum   = (float*)(ws + OFF_BSUM);
    unsigned* bar    = (unsigned*)(ws + OFF_BAR);
    _Float16* seq    = (_Float16*)(ws + OFF_SEQ);
    float*    outp   = (float*)d_out;

    hipLaunchKernelGGL(prep_kernel, dim3(1024), dim3(256), 0, stream,
                       Wih, Whh, bih, bhh, x, Wout,
                       wsum16, wih16, wout16, x16, bsum, bar);

    void* args[] = { &wsum16, &wih16, &wout16, &x16, &bsum,
                     (void*)&bout, &seq, &outp, &bar };
    hipLaunchCooperativeKernel((void*)lstm_kernel, dim3(NWG), dim3(NTHR),
                               args, 0, stream);
}

// Round 2
// 3531.992 us; speedup vs baseline: 1.2220x; 1.2220x over previous
//
#include <hip/hip_runtime.h>

typedef _Float16 half8 __attribute__((ext_vector_type(8)));
typedef _Float16 half4 __attribute__((ext_vector_type(4)));
typedef float    f32x4 __attribute__((ext_vector_type(4)));

constexpr int Bt   = 256;   // batch
constexpr int Hd   = 1024;  // hidden
constexpr int G4   = 4096;  // 4*H
constexpr int Ts   = 128;   // time steps
constexpr int DOUT = 128;

constexpr int NGROUP   = 8;    // independent batch groups (one per XCD ideally)
constexpr int WG_PER_G = 32;   // WGs per group
constexpr int NWG      = NGROUP * WG_PER_G;  // 256
constexpr int NTHR     = 512;  // 8 waves
constexpr int GROWS    = Bt / NGROUP;        // 32 batch rows per group

// workspace layout (bytes)
constexpr size_t OFF_WSUM = 0;                                // [4096][1024] f16
constexpr size_t OFF_WIH  = OFF_WSUM + (size_t)G4 * Hd * 2;   // [4096][1024] f16
constexpr size_t OFF_WOUT = OFF_WIH  + (size_t)G4 * Hd * 2;   // [128][1024] f16
constexpr size_t OFF_X    = OFF_WOUT + (size_t)DOUT * Hd * 2; // [256][1024] f16
constexpr size_t OFF_BSUM = OFF_X    + (size_t)Bt * Hd * 2;   // [4096] f32
constexpr size_t OFF_BAR  = OFF_BSUM + (size_t)G4 * 4;        // 8 groups x 256B
constexpr size_t OFF_SEQ  = OFF_BAR  + 4096;                  // [128][256][1024] f16
constexpr size_t WS_NEED  = OFF_SEQ  + (size_t)Ts * Bt * Hd * 2;

__device__ __forceinline__ float fast_sig(float x) {
    return 1.f / (1.f + __expf(-x));
}
__device__ __forceinline__ float fast_tanh(float x) {
    float ax = fabsf(x);
    float e  = __expf(-2.f * ax);
    float t  = (1.f - e) / (1.f + e);
    return copysignf(t, x);
}

__device__ __forceinline__ void gload_lds16(const void* g, void* l) {
    __builtin_amdgcn_global_load_lds(
        (const __attribute__((address_space(1))) void*)g,
        (__attribute__((address_space(3))) void*)l, 16, 0, 0);
}

// ---------------- precompute: f16 casts, W_sum, b_sum, barrier init ----------------
__global__ void prep_kernel(const float* __restrict__ Wih, const float* __restrict__ Whh,
                            const float* __restrict__ bih, const float* __restrict__ bhh,
                            const float* __restrict__ x,   const float* __restrict__ Wout,
                            _Float16* __restrict__ wsum16, _Float16* __restrict__ wih16,
                            _Float16* __restrict__ wout16, _Float16* __restrict__ x16,
                            float* __restrict__ bsum, unsigned* __restrict__ bar) {
    const int i0     = blockIdx.x * blockDim.x + threadIdx.x;
    const int stride = gridDim.x * blockDim.x;

    for (int i = i0; i < G4 * Hd / 4; i += stride) {
        f32x4 a = ((const f32x4*)Wih)[i];
        f32x4 b = ((const f32x4*)Whh)[i];
        half4 hs, hi;
        #pragma unroll
        for (int j = 0; j < 4; ++j) {
            hs[j] = (_Float16)(a[j] + b[j]);
            hi[j] = (_Float16)a[j];
        }
        ((half4*)wsum16)[i] = hs;
        ((half4*)wih16)[i]  = hi;
    }
    for (int i = i0; i < DOUT * Hd / 4; i += stride) {
        f32x4 a = ((const f32x4*)Wout)[i];
        half4 h;
        #pragma unroll
        for (int j = 0; j < 4; ++j) h[j] = (_Float16)a[j];
        ((half4*)wout16)[i] = h;
    }
    for (int i = i0; i < Bt * Hd / 4; i += stride) {
        f32x4 a = ((const f32x4*)x)[i];
        half4 h;
        #pragma unroll
        for (int j = 0; j < 4; ++j) h[j] = (_Float16)a[j];
        ((half4*)x16)[i] = h;
    }
    for (int i = i0; i < G4; i += stride) bsum[i] = bih[i] + bhh[i];
    for (int i = i0; i < 1024; i += stride) bar[i] = 0u;  // 4 KB of flags
}

// ---------------- persistent group-parallel LSTM ----------------
// group g = bid%8 owns batch rows [g*32, g*32+32). WG wgi = bid/8 covers j-cols
// [wgi*32, wgi*32+32). 8 waves = 2 j-subgroups x 4 K-splits. Each wave holds
// W_sum fragments for (4 gates x 16 cols x 256 K) in 128 VGPRs.
__launch_bounds__(NTHR, 2)
__global__ void lstm_kernel(const _Float16* __restrict__ wsum16,
                            const _Float16* __restrict__ wih16,
                            const _Float16* __restrict__ wout16,
                            const _Float16* __restrict__ x16,
                            const float* __restrict__ bsum,
                            const float* __restrict__ bout,
                            _Float16* __restrict__ seq,
                            float* __restrict__ out,
                            unsigned* __restrict__ bar) {
    __shared__ char smem[65536];  // A-tile [32][1024] f16 (64KB); reused for K-reduce

    const int bid = blockIdx.x;
    const int g   = bid & 7;           // group
    const int wgi = bid >> 3;          // 0..31
    const int tid = threadIdx.x;
    const int wv  = tid >> 6;          // wave 0..7
    const int l   = tid & 63;
    const int lr  = l & 15;
    const int lk  = l >> 4;
    const int ks  = wv & 3;            // K-split (256-wide)
    const int jg  = wv >> 2;           // 0..1
    const int j0  = wgi * 32 + jg * 16;
    const int brow0 = g * GROWS;

    unsigned* cnt = bar + g * 64;
    unsigned* gen = bar + g * 64 + 32;

    float bias[4];
    #pragma unroll
    for (int gg = 0; gg < 4; ++gg) bias[gg] = bsum[gg * Hd + j0 + lr];

    half8 Bf[4][8];
    auto loadB = [&](const _Float16* __restrict__ W) {
        #pragma unroll
        for (int gg = 0; gg < 4; ++gg)
            #pragma unroll
            for (int kk = 0; kk < 8; ++kk)
                Bf[gg][kk] = *(const half8*)(W + (size_t)(gg * Hd + j0 + lr) * Hd
                                               + ks * 256 + kk * 32 + lk * 8);
    };

    // stage A[32][1024] f16 -> LDS with XOR-swizzle (16B blocks, bb ^= row&7),
    // via pre-swizzled global source + linear global_load_lds dest.
    auto stageA = [&](const _Float16* __restrict__ Asrc) {
        #pragma unroll
        for (int s = 0; s < 8; ++s) {
            const int i   = wv * 8 + s;       // 0..63, 1KB each
            const int row = i >> 1;
            const int bb  = (i & 1) * 64 + l; // dest 16B-block within row
            const int gb  = bb ^ (row & 7);   // pre-swizzled source block
            gload_lds16((const char*)(Asrc + (size_t)row * Hd) + gb * 16,
                        smem + i * 1024);
        }
    };

    f32x4 c0 = {0.f,0.f,0.f,0.f}, c1 = {0.f,0.f,0.f,0.f};

    loadB(wih16);

    #pragma unroll 1
    for (int t = 0; t < Ts; ++t) {
        if (t > 0) {
            if (tid == 0) {
                while (__hip_atomic_load(gen, __ATOMIC_ACQUIRE, __HIP_MEMORY_SCOPE_AGENT)
                       < (unsigned)t)
                    __builtin_amdgcn_s_sleep(1);
            }
            __syncthreads();
        }

        const _Float16* Asrc = (t == 0)
            ? (x16 + (size_t)brow0 * Hd)
            : (seq + ((size_t)(t - 1) * Bt + brow0) * Hd);
        stageA(Asrc);
        __syncthreads();   // drains vmcnt for global_load_lds

        f32x4 acc[2][4];
        #pragma unroll
        for (int m = 0; m < 2; ++m)
            #pragma unroll
            for (int gg = 0; gg < 4; ++gg) acc[m][gg] = f32x4{0.f,0.f,0.f,0.f};

        #pragma unroll
        for (int kk = 0; kk < 8; ++kk) {
            half8 a[2];
            #pragma unroll
            for (int m = 0; m < 2; ++m) {
                const int row = m * 16 + lr;
                const int bb  = (ks * 32 + kk * 4 + lk) ^ (row & 7);
                a[m] = *(const half8*)(smem + row * 2048 + bb * 16);
            }
            #pragma unroll
            for (int gg = 0; gg < 4; ++gg) {
                acc[0][gg] = __builtin_amdgcn_mfma_f32_16x16x32_f16(a[0], Bf[gg][kk], acc[0][gg], 0,0,0);
                acc[1][gg] = __builtin_amdgcn_mfma_f32_16x16x32_f16(a[1], Bf[gg][kk], acc[1][gg], 0,0,0);
            }
        }
        __syncthreads();   // all A reads done; smem becomes reduce buffer

        if (ks != 0) {
            float* dst = (float*)(smem + (size_t)(jg * 3 + (ks - 1)) * 8192);
            #pragma unroll
            for (int i = 0; i < 8; ++i)
                *(f32x4*)(dst + i * 256 + l * 4) = acc[i >> 2][i & 3];
        }
        __syncthreads();

        if (ks == 0) {
            #pragma unroll
            for (int s = 0; s < 3; ++s) {
                const float* src = (const float*)(smem + (size_t)(jg * 3 + s) * 8192);
                #pragma unroll
                for (int i = 0; i < 8; ++i)
                    acc[i >> 2][i & 3] += *(const f32x4*)(src + i * 256 + l * 4);
            }
            _Float16* hrow = seq + (size_t)t * Bt * Hd;
            #pragma unroll
            for (int m = 0; m < 2; ++m) {
                f32x4& cc = m ? c1 : c0;
                #pragma unroll
                for (int r = 0; r < 4; ++r) {
                    float ig = fast_sig (acc[m][0][r] + bias[0]);
                    float fg = fast_sig (acc[m][1][r] + bias[1]);
                    float gv = fast_tanh(acc[m][2][r] + bias[2]);
                    float og = fast_sig (acc[m][3][r] + bias[3]);
                    float cn = fg * cc[r] + ig * gv;
                    cc[r] = cn;
                    float hv = og * fast_tanh(cn);
                    hrow[(size_t)(brow0 + m * 16 + lk * 4 + r) * Hd + j0 + lr] = (_Float16)hv;
                }
            }
            __threadfence();  // make h stores agent-visible before the flag
        }
        __syncthreads();

        if (tid == 0) {
            unsigned old = __hip_atomic_fetch_add(cnt, 1u, __ATOMIC_ACQ_REL, __HIP_MEMORY_SCOPE_AGENT);
            if (old == (unsigned)WG_PER_G - 1u) {
                __hip_atomic_store(cnt, 0u, __ATOMIC_RELAXED, __HIP_MEMORY_SCOPE_AGENT);
                __hip_atomic_fetch_add(gen, 1u, __ATOMIC_ACQ_REL, __HIP_MEMORY_SCOPE_AGENT);
            }
        }
        if (t == 0) loadB(wsum16);  // switch to W_sum for t >= 1
    }

    // wait for own group's final step
    if (tid == 0) {
        while (__hip_atomic_load(gen, __ATOMIC_ACQUIRE, __HIP_MEMORY_SCOPE_AGENT)
               < (unsigned)Ts)
            __builtin_amdgcn_s_sleep(1);
    }
    __syncthreads();

    // ---------------- fused output projection (group-local rows only) ----------------
    // wave task: one 16-row M-tile of seq restricted to this group's batch rows.
    {
        const int idx  = wgi * 8 + wv;          // 0..255
        const int t_   = idx >> 1;              // 0..127
        const int bb16 = brow0 + (idx & 1) * 16;
        const _Float16* abase = seq + ((size_t)t_ * Bt + bb16 + lr) * Hd + lk * 8;

        f32x4 oacc[8];
        #pragma unroll
        for (int ni = 0; ni < 8; ++ni) oacc[ni] = f32x4{0.f,0.f,0.f,0.f};

        #pragma unroll 2
        for (int k0 = 0; k0 < Hd; k0 += 32) {
            half8 a = *(const half8*)(abase + k0);
            #pragma unroll
            for (int ni = 0; ni < 8; ++ni) {
                half8 bf = *(const half8*)(wout16 + (size_t)(ni * 16 + lr) * Hd + lk * 8 + k0);
                oacc[ni] = __builtin_amdgcn_mfma_f32_16x16x32_f16(a, bf, oacc[ni], 0,0,0);
            }
        }
        #pragma unroll
        for (int ni = 0; ni < 8; ++ni) {
            const int d  = ni * 16 + lr;
            const float bo = bout[d];
            #pragma unroll
            for (int r = 0; r < 4; ++r) {
                const int b = bb16 + lk * 4 + r;
                out[(size_t)b * (Ts * DOUT) + t_ * DOUT + d] = oacc[ni][r] + bo;
            }
        }
    }
}

extern "C" void kernel_launch(void* const* d_in, const int* in_sizes, int n_in,
                              void* d_out, int out_size, void* d_ws, size_t ws_size,
                              hipStream_t stream) {
    const float* x    = (const float*)d_in[0];
    const float* Wih  = (const float*)d_in[1];
    const float* Whh  = (const float*)d_in[2];
    const float* bih  = (const float*)d_in[3];
    const float* bhh  = (const float*)d_in[4];
    const float* Wout = (const float*)d_in[5];
    const float* bout = (const float*)d_in[6];

    if (ws_size < WS_NEED) return;

    char* ws = (char*)d_ws;
    _Float16* wsum16 = (_Float16*)(ws + OFF_WSUM);
    _Float16* wih16  = (_Float16*)(ws + OFF_WIH);
    _Float16* wout16 = (_Float16*)(ws + OFF_WOUT);
    _Float16* x16    = (_Float16*)(ws + OFF_X);
    float*    bsum   = (float*)(ws + OFF_BSUM);
    unsigned* bar    = (unsigned*)(ws + OFF_BAR);
    _Float16* seq    = (_Float16*)(ws + OFF_SEQ);
    float*    outp   = (float*)d_out;

    hipLaunchKernelGGL(prep_kernel, dim3(1024), dim3(256), 0, stream,
                       Wih, Whh, bih, bhh, x, Wout,
                       wsum16, wih16, wout16, x16, bsum, bar);

    void* args[] = { &wsum16, &wih16, &wout16, &x16, &bsum,
                     (void*)&bout, &seq, &outp, &bar };
    hipLaunchCooperativeKernel((void*)lstm_kernel, dim3(NWG), dim3(NTHR),
                               args, 0, stream);
}

// Round 3
// 1368.510 us; speedup vs baseline: 3.1538x; 2.5809x over previous
//
#include <hip/hip_runtime.h>

typedef _Float16 half8 __attribute__((ext_vector_type(8)));
typedef _Float16 half4 __attribute__((ext_vector_type(4)));
typedef float    f32x4 __attribute__((ext_vector_type(4)));
typedef unsigned long long u64x2 __attribute__((ext_vector_type(2)));

constexpr int Bt   = 256;   // batch
constexpr int Hd   = 1024;  // hidden
constexpr int G4   = 4096;  // 4*H
constexpr int Ts   = 128;   // time steps
constexpr int DOUT = 128;

constexpr int NGROUP   = 8;    // independent batch groups
constexpr int WG_PER_G = 32;   // WGs per group
constexpr int NWG      = NGROUP * WG_PER_G;  // 256
constexpr int NTHR     = 512;  // 8 waves
constexpr int GROWS    = Bt / NGROUP;        // 32 batch rows per group

// workspace layout (bytes)
constexpr size_t OFF_WSUM = 0;                                // [4096][1024] f16
constexpr size_t OFF_WIH  = OFF_WSUM + (size_t)G4 * Hd * 2;   // [4096][1024] f16
constexpr size_t OFF_WOUT = OFF_WIH  + (size_t)G4 * Hd * 2;   // [128][1024] f16
constexpr size_t OFF_X    = OFF_WOUT + (size_t)DOUT * Hd * 2; // [256][1024] f16
constexpr size_t OFF_BSUM = OFF_X    + (size_t)Bt * Hd * 2;   // [4096] f32
constexpr size_t OFF_BAR  = OFF_BSUM + (size_t)G4 * 4;        // 8 groups x 64 slots
constexpr size_t OFF_SEQ  = OFF_BAR  + 4096;                  // [128][256][1024] f16
constexpr size_t WS_NEED  = OFF_SEQ  + (size_t)Ts * Bt * Hd * 2;

__device__ __forceinline__ float fast_sig(float x) {
    return 1.f / (1.f + __expf(-x));
}
__device__ __forceinline__ float fast_tanh(float x) {
    float ax = fabsf(x);
    float e  = __expf(-2.f * ax);
    float t  = (1.f - e) / (1.f + e);
    return copysignf(t, x);
}

__device__ __forceinline__ void gload_lds16(const void* g, void* l) {
    __builtin_amdgcn_global_load_lds(
        (const __attribute__((address_space(1))) void*)g,
        (__attribute__((address_space(3))) void*)l, 16, 0, 0);
}

// ---------------- precompute: f16 casts, W_sum, b_sum, flag init ----------------
__global__ void prep_kernel(const float* __restrict__ Wih, const float* __restrict__ Whh,
                            const float* __restrict__ bih, const float* __restrict__ bhh,
                            const float* __restrict__ x,   const float* __restrict__ Wout,
                            _Float16* __restrict__ wsum16, _Float16* __restrict__ wih16,
                            _Float16* __restrict__ wout16, _Float16* __restrict__ x16,
                            float* __restrict__ bsum, unsigned* __restrict__ bar) {
    const int i0     = blockIdx.x * blockDim.x + threadIdx.x;
    const int stride = gridDim.x * blockDim.x;

    for (int i = i0; i < G4 * Hd / 4; i += stride) {
        f32x4 a = ((const f32x4*)Wih)[i];
        f32x4 b = ((const f32x4*)Whh)[i];
        half4 hs, hi;
        #pragma unroll
        for (int j = 0; j < 4; ++j) {
            hs[j] = (_Float16)(a[j] + b[j]);
            hi[j] = (_Float16)a[j];
        }
        ((half4*)wsum16)[i] = hs;
        ((half4*)wih16)[i]  = hi;
    }
    for (int i = i0; i < DOUT * Hd / 4; i += stride) {
        f32x4 a = ((const f32x4*)Wout)[i];
        half4 h;
        #pragma unroll
        for (int j = 0; j < 4; ++j) h[j] = (_Float16)a[j];
        ((half4*)wout16)[i] = h;
    }
    for (int i = i0; i < Bt * Hd / 4; i += stride) {
        f32x4 a = ((const f32x4*)x)[i];
        half4 h;
        #pragma unroll
        for (int j = 0; j < 4; ++j) h[j] = (_Float16)a[j];
        ((half4*)x16)[i] = h;
    }
    for (int i = i0; i < G4; i += stride) bsum[i] = bih[i] + bhh[i];
    // flag slots: init at the MALL coherence point (bypass L2) so the
    // persistent kernel's sc1 polls see them regardless of dispatch flush.
    for (int i = i0; i < 1024; i += stride)
        __hip_atomic_store(bar + i, 0u, __ATOMIC_RELAXED, __HIP_MEMORY_SCOPE_AGENT);
}

// ---------------- persistent group-parallel LSTM ----------------
// group g = bid%8 owns batch rows [g*32, g*32+32). WG wgi = bid/8 covers j-cols
// [wgi*32, wgi*32+32). 8 waves = 2 j-subgroups x 4 K-splits. Each wave holds
// W fragments (4 gates x 16 cols x 256 K) in 128 VGPRs.
// Sync: NO fences, NO RMW. h handoff via relaxed agent (sc1/MALL) atomic
// stores; per-lead-wave flag slots (64/group) written after vmcnt(0); waiters
// poll all 64 slots with one wave-wide relaxed atomic load + __all.
__launch_bounds__(NTHR, 2)
__global__ void lstm_kernel(const _Float16* __restrict__ wsum16,
                            const _Float16* __restrict__ wih16,
                            const _Float16* __restrict__ wout16,
                            const _Float16* __restrict__ x16,
                            const float* __restrict__ bsum,
                            const float* __restrict__ bout,
                            _Float16* __restrict__ seq,
                            float* __restrict__ out,
                            unsigned* __restrict__ bar) {
    __shared__ char smem[65536];  // A-tile [32][1024] f16; reused: K-reduce + hstage

    const int bid = blockIdx.x;
    const int g   = bid & 7;           // group
    const int wgi = bid >> 3;          // 0..31
    const int tid = threadIdx.x;
    const int wv  = tid >> 6;          // wave 0..7
    const int l   = tid & 63;
    const int lr  = l & 15;
    const int lk  = l >> 4;
    const int ks  = wv & 3;            // K-split (256-wide)
    const int jg  = wv >> 2;           // 0..1
    const int j0  = wgi * 32 + jg * 16;
    const int brow0 = g * GROWS;

    unsigned* flags = bar + g * 64;    // 64 slots for this group

    float bias[4];
    #pragma unroll
    for (int gg = 0; gg < 4; ++gg) bias[gg] = bsum[gg * Hd + j0 + lr];

    half8 Bf[4][8];
    auto loadB = [&](const _Float16* __restrict__ W) {
        #pragma unroll
        for (int gg = 0; gg < 4; ++gg)
            #pragma unroll
            for (int kk = 0; kk < 8; ++kk)
                Bf[gg][kk] = *(const half8*)(W + (size_t)(gg * Hd + j0 + lr) * Hd
                                               + ks * 256 + kk * 32 + lk * 8);
    };

    // stage A[32][1024] f16 -> LDS with XOR-swizzle (16B blocks, bb ^= row&7),
    // via pre-swizzled global source + linear global_load_lds dest.
    auto stageA = [&](const _Float16* __restrict__ Asrc) {
        #pragma unroll
        for (int s = 0; s < 8; ++s) {
            const int i   = wv * 8 + s;       // 0..63, 1KB each
            const int row = i >> 1;
            const int bb  = (i & 1) * 64 + l; // dest 16B-block within row
            const int gb  = bb ^ (row & 7);   // pre-swizzled source block
            gload_lds16((const char*)(Asrc + (size_t)row * Hd) + gb * 16,
                        smem + i * 1024);
        }
    };

    f32x4 c0 = {0.f,0.f,0.f,0.f}, c1 = {0.f,0.f,0.f,0.f};

    loadB(wih16);

    #pragma unroll 1
    for (int t = 0; t < Ts; ++t) {
        if (t > 0) {
            if (wv == 0) {  // whole wave polls 64 slots in one sc1 load
                const unsigned tgt = (unsigned)t;
                while (true) {
                    unsigned v = __hip_atomic_load(flags + l, __ATOMIC_RELAXED,
                                                   __HIP_MEMORY_SCOPE_AGENT);
                    if (__all(v >= tgt)) break;
                    __builtin_amdgcn_s_sleep(2);
                }
            }
            __syncthreads();
        }

        const _Float16* Asrc = (t == 0)
            ? (x16 + (size_t)brow0 * Hd)
            : (seq + ((size_t)(t - 1) * Bt + brow0) * Hd);
        stageA(Asrc);
        __syncthreads();   // drains vmcnt for global_load_lds

        f32x4 acc[2][4];
        #pragma unroll
        for (int m = 0; m < 2; ++m)
            #pragma unroll
            for (int gg = 0; gg < 4; ++gg) acc[m][gg] = f32x4{0.f,0.f,0.f,0.f};

        #pragma unroll
        for (int kk = 0; kk < 8; ++kk) {
            half8 a[2];
            #pragma unroll
            for (int m = 0; m < 2; ++m) {
                const int row = m * 16 + lr;
                const int bb  = (ks * 32 + kk * 4 + lk) ^ (row & 7);
                a[m] = *(const half8*)(smem + row * 2048 + bb * 16);
            }
            #pragma unroll
            for (int gg = 0; gg < 4; ++gg) {
                acc[0][gg] = __builtin_amdgcn_mfma_f32_16x16x32_f16(a[0], Bf[gg][kk], acc[0][gg], 0,0,0);
                acc[1][gg] = __builtin_amdgcn_mfma_f32_16x16x32_f16(a[1], Bf[gg][kk], acc[1][gg], 0,0,0);
            }
        }
        __syncthreads();   // all A reads done; smem becomes reduce buffer

        if (ks != 0) {
            float* dst = (float*)(smem + (size_t)(jg * 3 + (ks - 1)) * 8192);
            #pragma unroll
            for (int i = 0; i < 8; ++i)
                *(f32x4*)(dst + i * 256 + l * 4) = acc[i >> 2][i & 3];
        }
        __syncthreads();

        char* hst = smem + 49152;  // [32 rows][32 cols] f16 staging (2 KB)
        if (ks == 0) {
            #pragma unroll
            for (int s = 0; s < 3; ++s) {
                const float* src = (const float*)(smem + (size_t)(jg * 3 + s) * 8192);
                #pragma unroll
                for (int i = 0; i < 8; ++i)
                    acc[i >> 2][i & 3] += *(const f32x4*)(src + i * 256 + l * 4);
            }
            #pragma unroll
            for (int m = 0; m < 2; ++m) {
                f32x4& cc = m ? c1 : c0;
                #pragma unroll
                for (int r = 0; r < 4; ++r) {
                    float ig = fast_sig (acc[m][0][r] + bias[0]);
                    float fg = fast_sig (acc[m][1][r] + bias[1]);
                    float gv = fast_tanh(acc[m][2][r] + bias[2]);
                    float og = fast_sig (acc[m][3][r] + bias[3]);
                    float cn = fg * cc[r] + ig * gv;
                    cc[r] = cn;
                    float hv = og * fast_tanh(cn);
                    *(_Float16*)(hst + (m * 16 + lk * 4 + r) * 64 + (jg * 16 + lr) * 2)
                        = (_Float16)hv;
                }
            }
        }
        __syncthreads();  // hstage complete

        if (ks == 0) {    // waves 0 and 4: push h to MALL, then own flag slot
            const int i   = (wv >> 2) * 64 + l;   // 0..127
            const int row = i >> 2;
            const int q   = i & 3;
            u64x2 v = *(const u64x2*)(hst + row * 64 + q * 16);
            size_t e = (size_t)t * Bt * Hd + (size_t)(brow0 + row) * Hd + wgi * 32 + q * 8;
            unsigned long long* gp = (unsigned long long*)(seq + e);
            __hip_atomic_store(gp,     v[0], __ATOMIC_RELAXED, __HIP_MEMORY_SCOPE_AGENT);
            __hip_atomic_store(gp + 1, v[1], __ATOMIC_RELAXED, __HIP_MEMORY_SCOPE_AGENT);
            asm volatile("s_waitcnt vmcnt(0)" ::: "memory");  // h committed at MALL
            if (l == 0)
                __hip_atomic_store(flags + wgi * 2 + (wv >> 2), (unsigned)(t + 1),
                                   __ATOMIC_RELAXED, __HIP_MEMORY_SCOPE_AGENT);
        }

        if (t == 0) loadB(wsum16);  // switch to W_sum for t >= 1
    }

    // wait for own group's final step
    if (wv == 0) {
        while (true) {
            unsigned v = __hip_atomic_load(flags + l, __ATOMIC_RELAXED,
                                           __HIP_MEMORY_SCOPE_AGENT);
            if (__all(v >= (unsigned)Ts)) break;
            __builtin_amdgcn_s_sleep(2);
        }
    }
    __syncthreads();

    // ---------------- fused output projection (group-local rows only) ----------------
    {
        const int idx  = wgi * 8 + wv;          // 0..255
        const int t_   = idx >> 1;              // 0..127
        const int bb16 = brow0 + (idx & 1) * 16;
        const _Float16* abase = seq + ((size_t)t_ * Bt + bb16 + lr) * Hd + lk * 8;

        f32x4 oacc[8];
        #pragma unroll
        for (int ni = 0; ni < 8; ++ni) oacc[ni] = f32x4{0.f,0.f,0.f,0.f};

        #pragma unroll 2
        for (int k0 = 0; k0 < Hd; k0 += 32) {
            half8 a = *(const half8*)(abase + k0);
            #pragma unroll
            for (int ni = 0; ni < 8; ++ni) {
                half8 bf = *(const half8*)(wout16 + (size_t)(ni * 16 + lr) * Hd + lk * 8 + k0);
                oacc[ni] = __builtin_amdgcn_mfma_f32_16x16x32_f16(a, bf, oacc[ni], 0,0,0);
            }
        }
        #pragma unroll
        for (int ni = 0; ni < 8; ++ni) {
            const int d  = ni * 16 + lr;
            const float bo = bout[d];
            #pragma unroll
            for (int r = 0; r < 4; ++r) {
                const int b = bb16 + lk * 4 + r;
                out[(size_t)b * (Ts * DOUT) + t_ * DOUT + d] = oacc[ni][r] + bo;
            }
        }
    }
}

extern "C" void kernel_launch(void* const* d_in, const int* in_sizes, int n_in,
                              void* d_out, int out_size, void* d_ws, size_t ws_size,
                              hipStream_t stream) {
    const float* x    = (const float*)d_in[0];
    const float* Wih  = (const float*)d_in[1];
    const float* Whh  = (const float*)d_in[2];
    const float* bih  = (const float*)d_in[3];
    const float* bhh  = (const float*)d_in[4];
    const float* Wout = (const float*)d_in[5];
    const float* bout = (const float*)d_in[6];

    if (ws_size < WS_NEED) return;

    char* ws = (char*)d_ws;
    _Float16* wsum16 = (_Float16*)(ws + OFF_WSUM);
    _Float16* wih16  = (_Float16*)(ws + OFF_WIH);
    _Float16* wout16 = (_Float16*)(ws + OFF_WOUT);
    _Float16* x16    = (_Float16*)(ws + OFF_X);
    float*    bsum   = (float*)(ws + OFF_BSUM);
    unsigned* bar    = (unsigned*)(ws + OFF_BAR);
    _Float16* seq    = (_Float16*)(ws + OFF_SEQ);
    float*    outp   = (float*)d_out;

    hipLaunchKernelGGL(prep_kernel, dim3(1024), dim3(256), 0, stream,
                       Wih, Whh, bih, bhh, x, Wout,
                       wsum16, wih16, wout16, x16, bsum, bar);

    void* args[] = { &wsum16, &wih16, &wout16, &x16, &bsum,
                     (void*)&bout, &seq, &outp, &bar };
    hipLaunchCooperativeKernel((void*)lstm_kernel, dim3(NWG), dim3(NTHR),
                               args, 0, stream);
}

// Round 4
// 1095.602 us; speedup vs baseline: 3.9393x; 1.2491x over previous
//
#include <hip/hip_runtime.h>

typedef _Float16 half8 __attribute__((ext_vector_type(8)));
typedef _Float16 half4 __attribute__((ext_vector_type(4)));
typedef float    f32x4 __attribute__((ext_vector_type(4)));
typedef unsigned long long u64x2 __attribute__((ext_vector_type(2)));

constexpr int Bt   = 256;   // batch
constexpr int Hd   = 1024;  // hidden
constexpr int G4   = 4096;  // 4*H
constexpr int Ts   = 128;   // time steps
constexpr int DOUT = 128;

constexpr int NGROUP   = 8;    // independent batch groups
constexpr int WG_PER_G = 32;   // WGs per group
constexpr int NWG      = NGROUP * WG_PER_G;  // 256
constexpr int NTHR     = 512;  // 8 waves
constexpr int GROWS    = Bt / NGROUP;        // 32 batch rows per group

// workspace layout (bytes)
constexpr size_t OFF_WSUM = 0;                                // [4096][1024] f16
constexpr size_t OFF_WIH  = OFF_WSUM + (size_t)G4 * Hd * 2;   // [4096][1024] f16
constexpr size_t OFF_WOUT = OFF_WIH  + (size_t)G4 * Hd * 2;   // [128][1024] f16
constexpr size_t OFF_X    = OFF_WOUT + (size_t)DOUT * Hd * 2; // [256][1024] f16
constexpr size_t OFF_BSUM = OFF_X    + (size_t)Bt * Hd * 2;   // [4096] f32
constexpr size_t OFF_BAR  = OFF_BSUM + (size_t)G4 * 4;        // 8 groups x 64 slots
constexpr size_t OFF_SEQ  = OFF_BAR  + 4096;                  // [128][256][1024] f16
constexpr size_t WS_NEED  = OFF_SEQ  + (size_t)Ts * Bt * Hd * 2;

__device__ __forceinline__ float fast_sig(float x) {
    return 1.f / (1.f + __expf(-x));
}
__device__ __forceinline__ float fast_tanh(float x) {
    float ax = fabsf(x);
    float e  = __expf(-2.f * ax);
    float t  = (1.f - e) / (1.f + e);
    return copysignf(t, x);
}

__device__ __forceinline__ void gload_lds16(const void* g, void* l) {
    __builtin_amdgcn_global_load_lds(
        (const __attribute__((address_space(1))) void*)g,
        (__attribute__((address_space(3))) void*)l, 16, 0, 0);
}

// write-through 16B store: visible at the device coherence point after vmcnt(0)
__device__ __forceinline__ void store16_wt(void* gp, u64x2 v) {
    asm volatile("global_store_dwordx4 %0, %1, off sc0 sc1"
                 :: "v"(gp), "v"(v) : "memory");
}
__device__ __forceinline__ void store4_wt(unsigned* gp, unsigned v) {
    asm volatile("global_store_dword %0, %1, off sc0 sc1"
                 :: "v"(gp), "v"(v) : "memory");
}
__device__ __forceinline__ unsigned load4_cp(const unsigned* gp) {
    unsigned v;
    asm volatile("global_load_dword %0, %1, off sc0 sc1\n\t"
                 "s_waitcnt vmcnt(0)"
                 : "=v"(v) : "v"(gp) : "memory");
    return v;
}

// ---------------- precompute: f16 casts, W_sum, b_sum, flag init ----------------
__global__ void prep_kernel(const float* __restrict__ Wih, const float* __restrict__ Whh,
                            const float* __restrict__ bih, const float* __restrict__ bhh,
                            const float* __restrict__ x,   const float* __restrict__ Wout,
                            _Float16* __restrict__ wsum16, _Float16* __restrict__ wih16,
                            _Float16* __restrict__ wout16, _Float16* __restrict__ x16,
                            float* __restrict__ bsum, unsigned* __restrict__ bar) {
    const int i0     = blockIdx.x * blockDim.x + threadIdx.x;
    const int stride = gridDim.x * blockDim.x;

    for (int i = i0; i < G4 * Hd / 4; i += stride) {
        f32x4 a = ((const f32x4*)Wih)[i];
        f32x4 b = ((const f32x4*)Whh)[i];
        half4 hs, hi;
        #pragma unroll
        for (int j = 0; j < 4; ++j) {
            hs[j] = (_Float16)(a[j] + b[j]);
            hi[j] = (_Float16)a[j];
        }
        ((half4*)wsum16)[i] = hs;
        ((half4*)wih16)[i]  = hi;
    }
    for (int i = i0; i < DOUT * Hd / 4; i += stride) {
        f32x4 a = ((const f32x4*)Wout)[i];
        half4 h;
        #pragma unroll
        for (int j = 0; j < 4; ++j) h[j] = (_Float16)a[j];
        ((half4*)wout16)[i] = h;
    }
    for (int i = i0; i < Bt * Hd / 4; i += stride) {
        f32x4 a = ((const f32x4*)x)[i];
        half4 h;
        #pragma unroll
        for (int j = 0; j < 4; ++j) h[j] = (_Float16)a[j];
        ((half4*)x16)[i] = h;
    }
    for (int i = i0; i < G4; i += stride) bsum[i] = bih[i] + bhh[i];
    // init flags at the coherence point so sc0sc1 polls see zeros
    for (int i = i0; i < 1024; i += stride)
        __hip_atomic_store(bar + i, 0u, __ATOMIC_RELAXED, __HIP_MEMORY_SCOPE_AGENT);
}

// ---------------- persistent group-parallel LSTM ----------------
// group g = bid%8 owns batch rows [g*32, g*32+32). WG wgi = bid/8 covers j-cols
// [wgi*32, wgi*32+32). 8 waves = 2 j-subgroups x 4 K-splits. Each wave holds
// W fragments (4 gates x 16 cols x 256 K) in 128 VGPRs.
// Sync: h handoff = 2 wide write-through (sc0 sc1) stores on wave 0 +
// vmcnt(0) + ONE flag dword per WG. Waiters: one wave-wide sc0sc1 poll.
__launch_bounds__(NTHR, 2)
__global__ void lstm_kernel(const _Float16* __restrict__ wsum16,
                            const _Float16* __restrict__ wih16,
                            const _Float16* __restrict__ wout16,
                            const _Float16* __restrict__ x16,
                            const float* __restrict__ bsum,
                            const float* __restrict__ bout,
                            _Float16* __restrict__ seq,
                            float* __restrict__ out,
                            unsigned* __restrict__ bar) {
    __shared__ char smem[65536];  // A-tile [32][1024] f16; reused: K-reduce + hstage

    const int bid = blockIdx.x;
    const int g   = bid & 7;           // group
    const int wgi = bid >> 3;          // 0..31
    const int tid = threadIdx.x;
    const int wv  = tid >> 6;          // wave 0..7
    const int l   = tid & 63;
    const int lr  = l & 15;
    const int lk  = l >> 4;
    const int ks  = wv & 3;            // K-split (256-wide)
    const int jg  = wv >> 2;           // 0..1
    const int j0  = wgi * 32 + jg * 16;
    const int brow0 = g * GROWS;

    unsigned* flags = bar + g * 64;    // slots 0..31 used for this group

    float bias[4];
    #pragma unroll
    for (int gg = 0; gg < 4; ++gg) bias[gg] = bsum[gg * Hd + j0 + lr];

    half8 Bf[4][8];
    auto loadB = [&](const _Float16* __restrict__ W) {
        #pragma unroll
        for (int gg = 0; gg < 4; ++gg)
            #pragma unroll
            for (int kk = 0; kk < 8; ++kk)
                Bf[gg][kk] = *(const half8*)(W + (size_t)(gg * Hd + j0 + lr) * Hd
                                               + ks * 256 + kk * 32 + lk * 8);
    };

    // stage A[32][1024] f16 -> LDS with XOR-swizzle (16B blocks, bb ^= row&7),
    // via pre-swizzled global source + linear global_load_lds dest.
    auto stageA = [&](const _Float16* __restrict__ Asrc) {
        #pragma unroll
        for (int s = 0; s < 8; ++s) {
            const int i   = wv * 8 + s;       // 0..63, 1KB each
            const int row = i >> 1;
            const int bb  = (i & 1) * 64 + l; // dest 16B-block within row
            const int gb  = bb ^ (row & 7);   // pre-swizzled source block
            gload_lds16((const char*)(Asrc + (size_t)row * Hd) + gb * 16,
                        smem + i * 1024);
        }
    };

    f32x4 c0 = {0.f,0.f,0.f,0.f}, c1 = {0.f,0.f,0.f,0.f};

    loadB(wih16);

    #pragma unroll 1
    for (int t = 0; t < Ts; ++t) {
        if (t > 0) {
            if (wv == 0) {  // whole wave polls the 32 slots (dup to 64 lanes)
                const unsigned tgt = (unsigned)t;
                while (true) {
                    unsigned v = load4_cp(flags + (l & 31));
                    if (__all(v >= tgt)) break;
                    __builtin_amdgcn_s_sleep(1);
                }
            }
            __syncthreads();
        }

        const _Float16* Asrc = (t == 0)
            ? (x16 + (size_t)brow0 * Hd)
            : (seq + ((size_t)(t - 1) * Bt + brow0) * Hd);
        stageA(Asrc);
        __syncthreads();   // drains vmcnt for global_load_lds

        f32x4 acc[2][4];
        #pragma unroll
        for (int m = 0; m < 2; ++m)
            #pragma unroll
            for (int gg = 0; gg < 4; ++gg) acc[m][gg] = f32x4{0.f,0.f,0.f,0.f};

        #pragma unroll
        for (int kk = 0; kk < 8; ++kk) {
            half8 a[2];
            #pragma unroll
            for (int m = 0; m < 2; ++m) {
                const int row = m * 16 + lr;
                const int bb  = (ks * 32 + kk * 4 + lk) ^ (row & 7);
                a[m] = *(const half8*)(smem + row * 2048 + bb * 16);
            }
            #pragma unroll
            for (int gg = 0; gg < 4; ++gg) {
                acc[0][gg] = __builtin_amdgcn_mfma_f32_16x16x32_f16(a[0], Bf[gg][kk], acc[0][gg], 0,0,0);
                acc[1][gg] = __builtin_amdgcn_mfma_f32_16x16x32_f16(a[1], Bf[gg][kk], acc[1][gg], 0,0,0);
            }
        }
        __syncthreads();   // all A reads done; smem becomes reduce buffer

        if (ks != 0) {
            float* dst = (float*)(smem + (size_t)(jg * 3 + (ks - 1)) * 8192);
            #pragma unroll
            for (int i = 0; i < 8; ++i)
                *(f32x4*)(dst + i * 256 + l * 4) = acc[i >> 2][i & 3];
        }
        __syncthreads();

        char* hst = smem + 49152;  // [32 rows][32 cols] f16 staging (2 KB)
        if (ks == 0) {
            #pragma unroll
            for (int s = 0; s < 3; ++s) {
                const float* src = (const float*)(smem + (size_t)(jg * 3 + s) * 8192);
                #pragma unroll
                for (int i = 0; i < 8; ++i)
                    acc[i >> 2][i & 3] += *(const f32x4*)(src + i * 256 + l * 4);
            }
            #pragma unroll
            for (int m = 0; m < 2; ++m) {
                f32x4& cc = m ? c1 : c0;
                #pragma unroll
                for (int r = 0; r < 4; ++r) {
                    float ig = fast_sig (acc[m][0][r] + bias[0]);
                    float fg = fast_sig (acc[m][1][r] + bias[1]);
                    float gv = fast_tanh(acc[m][2][r] + bias[2]);
                    float og = fast_sig (acc[m][3][r] + bias[3]);
                    float cn = fg * cc[r] + ig * gv;
                    cc[r] = cn;
                    float hv = og * fast_tanh(cn);
                    *(_Float16*)(hst + (m * 16 + lk * 4 + r) * 64 + (jg * 16 + lr) * 2)
                        = (_Float16)hv;
                }
            }
        }
        __syncthreads();  // hstage complete

        if (wv == 0) {    // wave 0: 2 wide write-through stores + 1 flag
            _Float16* hbase = seq + (size_t)t * Bt * Hd;
            #pragma unroll
            for (int s = 0; s < 2; ++s) {
                const int row = s * 16 + (l >> 2);
                const int q   = l & 3;
                u64x2 v = *(const u64x2*)(hst + row * 64 + q * 16);
                store16_wt(hbase + (size_t)(brow0 + row) * Hd + wgi * 32 + q * 8, v);
            }
            asm volatile("s_waitcnt vmcnt(0)" ::: "memory");  // h committed
            if (l == 0) store4_wt(flags + wgi, (unsigned)(t + 1));
        }

        if (t == 0) loadB(wsum16);  // switch to W_sum for t >= 1
    }

    // wait for own group's final step
    if (wv == 0) {
        while (true) {
            unsigned v = load4_cp(flags + (l & 31));
            if (__all(v >= (unsigned)Ts)) break;
            __builtin_amdgcn_s_sleep(1);
        }
    }
    __syncthreads();

    // ---------------- fused output projection (group-local rows only) ----------------
    {
        const int idx  = wgi * 8 + wv;          // 0..255
        const int t_   = idx >> 1;              // 0..127
        const int bb16 = brow0 + (idx & 1) * 16;
        const _Float16* abase = seq + ((size_t)t_ * Bt + bb16 + lr) * Hd + lk * 8;

        f32x4 oacc[8];
        #pragma unroll
        for (int ni = 0; ni < 8; ++ni) oacc[ni] = f32x4{0.f,0.f,0.f,0.f};

        #pragma unroll 2
        for (int k0 = 0; k0 < Hd; k0 += 32) {
            half8 a = *(const half8*)(abase + k0);
            #pragma unroll
            for (int ni = 0; ni < 8; ++ni) {
                half8 bf = *(const half8*)(wout16 + (size_t)(ni * 16 + lr) * Hd + lk * 8 + k0);
                oacc[ni] = __builtin_amdgcn_mfma_f32_16x16x32_f16(a, bf, oacc[ni], 0,0,0);
            }
        }
        #pragma unroll
        for (int ni = 0; ni < 8; ++ni) {
            const int d  = ni * 16 + lr;
            const float bo = bout[d];
            #pragma unroll
            for (int r = 0; r < 4; ++r) {
                const int b = bb16 + lk * 4 + r;
                out[(size_t)b * (Ts * DOUT) + t_ * DOUT + d] = oacc[ni][r] + bo;
            }
        }
    }
}

extern "C" void kernel_launch(void* const* d_in, const int* in_sizes, int n_in,
                              void* d_out, int out_size, void* d_ws, size_t ws_size,
                              hipStream_t stream) {
    const float* x    = (const float*)d_in[0];
    const float* Wih  = (const float*)d_in[1];
    const float* Whh  = (const float*)d_in[2];
    const float* bih  = (const float*)d_in[3];
    const float* bhh  = (const float*)d_in[4];
    const float* Wout = (const float*)d_in[5];
    const float* bout = (const float*)d_in[6];

    if (ws_size < WS_NEED) return;

    char* ws = (char*)d_ws;
    _Float16* wsum16 = (_Float16*)(ws + OFF_WSUM);
    _Float16* wih16  = (_Float16*)(ws + OFF_WIH);
    _Float16* wout16 = (_Float16*)(ws + OFF_WOUT);
    _Float16* x16    = (_Float16*)(ws + OFF_X);
    float*    bsum   = (float*)(ws + OFF_BSUM);
    unsigned* bar    = (unsigned*)(ws + OFF_BAR);
    _Float16* seq    = (_Float16*)(ws + OFF_SEQ);
    float*    outp   = (float*)d_out;

    hipLaunchKernelGGL(prep_kernel, dim3(1024), dim3(256), 0, stream,
                       Wih, Whh, bih, bhh, x, Wout,
                       wsum16, wih16, wout16, x16, bsum, bar);

    void* args[] = { &wsum16, &wih16, &wout16, &x16, &bsum,
                     (void*)&bout, &seq, &outp, &bar };
    hipLaunchCooperativeKernel((void*)lstm_kernel, dim3(NWG), dim3(NTHR),
                               args, 0, stream);
}

// Round 5
// 985.465 us; speedup vs baseline: 4.3796x; 1.1118x over previous
//
#include <hip/hip_runtime.h>

typedef _Float16 half8 __attribute__((ext_vector_type(8)));
typedef _Float16 half4 __attribute__((ext_vector_type(4)));
typedef float    f32x4 __attribute__((ext_vector_type(4)));
typedef unsigned long long u64x2 __attribute__((ext_vector_type(2)));

constexpr int Bt   = 256;   // batch
constexpr int Hd   = 1024;  // hidden
constexpr int G4   = 4096;  // 4*H
constexpr int Ts   = 128;   // time steps
constexpr int DOUT = 128;

constexpr int NGROUP   = 8;    // independent batch groups
constexpr int WG_PER_G = 32;   // WGs per group
constexpr int NWG      = NGROUP * WG_PER_G;  // 256
constexpr int NTHR     = 512;  // 8 waves
constexpr int GROWS    = Bt / NGROUP;        // 32 rows per group (2 sub-blocks of 16)

// seq layout: [t][jb 0..31][256 rows][32 cols] f16  (step stride = 512 KB)
constexpr size_t SEQ_T = (size_t)32 * 256 * 64;   // bytes per step = 524288

// workspace layout (bytes)
constexpr size_t OFF_WSUM = 0;                                // [4096][1024] f16
constexpr size_t OFF_WIH  = OFF_WSUM + (size_t)G4 * Hd * 2;   // [4096][1024] f16
constexpr size_t OFF_WOUT = OFF_WIH  + (size_t)G4 * Hd * 2;   // [128][1024] f16
constexpr size_t OFF_X    = OFF_WOUT + (size_t)DOUT * Hd * 2; // blocked [32][256][32] f16
constexpr size_t OFF_BSUM = OFF_X    + (size_t)Bt * Hd * 2;   // [4096] f32
constexpr size_t OFF_BAR  = OFF_BSUM + (size_t)G4 * 4;        // 8 groups x 16 KB flags
constexpr size_t OFF_SEQ  = OFF_BAR  + 131072;                // [128] x 512 KB
constexpr size_t WS_NEED  = OFF_SEQ  + (size_t)Ts * SEQ_T;

__device__ __forceinline__ float fast_sig(float x) {
    return 1.f / (1.f + __expf(-x));
}
__device__ __forceinline__ float fast_tanh(float x) {
    float ax = fabsf(x);
    float e  = __expf(-2.f * ax);
    float t  = (1.f - e) / (1.f + e);
    return copysignf(t, x);
}

__device__ __forceinline__ void gload_lds16(const void* g, void* l) {
    __builtin_amdgcn_global_load_lds(
        (const __attribute__((address_space(1))) void*)g,
        (__attribute__((address_space(3))) void*)l, 16, 0, 0);
}
__device__ __forceinline__ void store16_wt(void* gp, u64x2 v) {
    asm volatile("global_store_dwordx4 %0, %1, off sc0 sc1"
                 :: "v"(gp), "v"(v) : "memory");
}
__device__ __forceinline__ void store4_wt(unsigned* gp, unsigned v) {
    asm volatile("global_store_dword %0, %1, off sc0 sc1"
                 :: "v"(gp), "v"(v) : "memory");
}
__device__ __forceinline__ unsigned load4_cp(const unsigned* gp) {
    unsigned v;
    asm volatile("global_load_dword %0, %1, off sc0 sc1\n\t"
                 "s_waitcnt vmcnt(0)"
                 : "=v"(v) : "v"(gp) : "memory");
    return v;
}

// ---------------- precompute ----------------
__global__ void prep_kernel(const float* __restrict__ Wih, const float* __restrict__ Whh,
                            const float* __restrict__ bih, const float* __restrict__ bhh,
                            const float* __restrict__ x,   const float* __restrict__ Wout,
                            _Float16* __restrict__ wsum16, _Float16* __restrict__ wih16,
                            _Float16* __restrict__ wout16, _Float16* __restrict__ x16,
                            float* __restrict__ bsum, unsigned* __restrict__ bar) {
    const int i0     = blockIdx.x * blockDim.x + threadIdx.x;
    const int stride = gridDim.x * blockDim.x;

    for (int i = i0; i < G4 * Hd / 4; i += stride) {
        f32x4 a = ((const f32x4*)Wih)[i];
        f32x4 b = ((const f32x4*)Whh)[i];
        half4 hs, hi;
        #pragma unroll
        for (int j = 0; j < 4; ++j) {
            hs[j] = (_Float16)(a[j] + b[j]);
            hi[j] = (_Float16)a[j];
        }
        ((half4*)wsum16)[i] = hs;
        ((half4*)wih16)[i]  = hi;
    }
    for (int i = i0; i < DOUT * Hd / 4; i += stride) {
        f32x4 a = ((const f32x4*)Wout)[i];
        half4 h;
        #pragma unroll
        for (int j = 0; j < 4; ++j) h[j] = (_Float16)a[j];
        ((half4*)wout16)[i] = h;
    }
    // x -> blocked f16 layout [jb][256 rows][32 cols]
    for (int i = i0; i < Bt * Hd / 4; i += stride) {
        f32x4 a = ((const f32x4*)x)[i];
        half4 h;
        #pragma unroll
        for (int j = 0; j < 4; ++j) h[j] = (_Float16)a[j];
        const int row = i >> 8;
        const int e   = (i & 255) * 4;     // col element 0..1023, /4 aligned
        const int jb  = e >> 5;
        const int c   = e & 31;
        ((half4*)x16)[(jb * 256 + row) * 8 + (c >> 2)] = h;
    }
    for (int i = i0; i < G4; i += stride) bsum[i] = bih[i] + bhh[i];
    for (int i = i0; i < 32768; i += stride)
        __hip_atomic_store(bar + i, 0u, __ATOMIC_RELAXED, __HIP_MEMORY_SCOPE_AGENT);
}

// ---------------- persistent pipelined LSTM ----------------
// group g=bid&7 owns rows [g*32,g*32+32) split into P=[+0,+16) Q=[+16,+32).
// WG wgi=bid>>3 covers j-cols [wgi*32,+32). 8 waves = 4 K-splits x 2 jg.
// While P's h(t) exchange is in flight, Q(t) computes, and vice versa.
// flags: per group 16KB: wgi*512B + {P0,P1,Q0,Q1}*128B lines; value = t+1.
__launch_bounds__(NTHR, 2)
__global__ void lstm_kernel(const _Float16* __restrict__ wsum16,
                            const _Float16* __restrict__ wih16,
                            const _Float16* __restrict__ wout16,
                            const _Float16* __restrict__ x16,
                            const float* __restrict__ bsum,
                            const float* __restrict__ bout,
                            _Float16* __restrict__ seq,
                            float* __restrict__ out,
                            unsigned* __restrict__ bar) {
    __shared__ char smem[65536];  // A_P at 0, A_Q at 32768 (each 32KB, reused for reduce+hstage)

    const int bid = blockIdx.x;
    const int g   = bid & 7;
    const int wgi = bid >> 3;
    const int tid = threadIdx.x;
    const int wv  = tid >> 6;
    const int l   = tid & 63;
    const int lr  = l & 15;
    const int lk  = l >> 4;
    const int ks  = wv & 3;            // K-split (256-wide)
    const int jg  = wv >> 2;           // 0..1
    const int j0  = wgi * 32 + jg * 16;
    const int brow0 = g * GROWS;
    const bool lead = (ks == 0);

    unsigned* gflags = bar + (size_t)g * 4096;   // dwords

    float bias[4];
    #pragma unroll
    for (int gg = 0; gg < 4; ++gg) bias[gg] = bsum[gg * Hd + j0 + lr];

    half8 Bf[4][8];
    auto loadB = [&](const _Float16* __restrict__ W) {
        #pragma unroll
        for (int gg = 0; gg < 4; ++gg)
            #pragma unroll
            for (int kk = 0; kk < 8; ++kk)
                Bf[gg][kk] = *(const half8*)(W + (size_t)(gg * Hd + j0 + lr) * Hd
                                               + ks * 256 + kk * 32 + lk * 8);
    };

    const char* x16c = (const char*)x16;
    char*       seqc = (char*)seq;

    // stage 16 rows x 1024 cols from blocked src into A region with XOR swizzle
    auto stageS = [&](char* Abase, const char* srcb, int rbase) {
        #pragma unroll
        for (int s = 0; s < 4; ++s) {
            const int i   = wv * 4 + s;           // 0..31 chunks of 1KB
            const int row = i >> 1;
            const int gb  = ((i & 1) * 64 + l) ^ (row & 7);  // logical 16B block
            const int jb  = gb >> 2;
            const int q   = gb & 3;
            gload_lds16(srcb + ((size_t)(jb * 256 + rbase + row)) * 64 + q * 16,
                        Abase + i * 1024);
        }
    };

    auto mfmaS = [&](char* Abase, f32x4* acc) {
        #pragma unroll
        for (int gg = 0; gg < 4; ++gg) acc[gg] = f32x4{0.f,0.f,0.f,0.f};
        #pragma unroll
        for (int kk = 0; kk < 8; ++kk) {
            const int bb = (ks * 32 + kk * 4 + lk) ^ (lr & 7);
            half8 a = *(const half8*)(Abase + lr * 2048 + bb * 16);
            #pragma unroll
            for (int gg = 0; gg < 4; ++gg)
                acc[gg] = __builtin_amdgcn_mfma_f32_16x16x32_f16(a, Bf[gg][kk], acc[gg], 0,0,0);
        }
    };

    auto dumpS = [&](char* Abase, const f32x4* acc) {   // ks != 0 waves
        char* dst = Abase + (size_t)(jg * 3 + (ks - 1)) * 4096;
        #pragma unroll
        for (int gg = 0; gg < 4; ++gg)
            *(f32x4*)(dst + gg * 1024 + l * 16) = acc[gg];
    };

    // leads: reduce partials, cell update, private LDS transpose, WT store h
    auto finishS = [&](char* Abase, f32x4* acc, f32x4& cc, int S, int t) {
        #pragma unroll
        for (int s = 0; s < 3; ++s) {
            const char* src = Abase + (size_t)(jg * 3 + s) * 4096;
            #pragma unroll
            for (int gg = 0; gg < 4; ++gg)
                acc[gg] += *(const f32x4*)(src + gg * 1024 + l * 16);
        }
        char* hst = Abase + 24576 + jg * 512;  // [16 rows][16 cols] f16
        #pragma unroll
        for (int r = 0; r < 4; ++r) {
            float ig = fast_sig (acc[0][r] + bias[0]);
            float fg = fast_sig (acc[1][r] + bias[1]);
            float gv = fast_tanh(acc[2][r] + bias[2]);
            float og = fast_sig (acc[3][r] + bias[3]);
            float cn = fg * cc[r] + ig * gv;
            cc[r] = cn;
            float hv = og * fast_tanh(cn);
            *(_Float16*)(hst + (lk * 4 + r) * 32 + lr * 2) = (_Float16)hv;
        }
        // private transpose read + write-through store (lanes 0..31)
        if (l < 32) {
            const int row = l >> 1;
            const int q   = l & 1;
            u64x2 v = *(const u64x2*)(hst + row * 32 + q * 16);
            char* gp = seqc + (size_t)t * SEQ_T
                     + ((size_t)(wgi * 256 + brow0 + S * 16 + row)) * 64
                     + jg * 32 + q * 16;
            store16_wt(gp, v);
        }
        asm volatile("s_waitcnt vmcnt(0)" ::: "memory");
        if (l == 0)
            store4_wt(gflags + wgi * 128 + S * 64 + jg * 32, (unsigned)(t + 1));
    };

    auto pollS = [&](int S, unsigned tgt) {   // wave 0 only; all 64 lanes
        const unsigned* p = gflags + (l & 31) * 128 + S * 64 + (l >> 5) * 32;
        while (true) {
            unsigned v = load4_cp(p);
            if (__all(v >= tgt)) break;
            __builtin_amdgcn_s_sleep(1);
        }
    };

    char* A_P = smem;
    char* A_Q = smem + 32768;
    f32x4 cP = {0.f,0.f,0.f,0.f}, cQ = {0.f,0.f,0.f,0.f};
    f32x4 acc[4];

    loadB(wih16);

    // prologue: stage P(0) from x
    stageS(A_P, x16c, brow0);
    __syncthreads();

    #pragma unroll 1
    for (int t = 0; t < Ts; ++t) {
        const char* srcQ = (t == 0) ? x16c : (seqc + (size_t)(t - 1) * SEQ_T);

        // ---- P phase: compute P(t); stage Q(t) meanwhile ----
        mfmaS(A_P, acc);
        __syncthreads();                     // A_P data dead
        if (wv == 0) pollS(1, (unsigned)t);  // Q inputs ready? (t=0 trivial)
        else if (!lead) dumpS(A_P, acc);
        __syncthreads();
        stageS(A_Q, srcQ, brow0 + 16);       // all waves: issue Q stage
        if (lead) finishS(A_P, acc, cP, 0, t);
        __syncthreads();                     // drains stageQ loads + lead stores

        // ---- Q phase: compute Q(t); stage P(t+1) meanwhile ----
        mfmaS(A_Q, acc);
        __syncthreads();
        if (t < Ts - 1) {
            if (wv == 0) pollS(0, (unsigned)(t + 1));  // P(t) from all WGs
            else if (!lead) dumpS(A_Q, acc);
            __syncthreads();
            stageS(A_P, seqc + (size_t)t * SEQ_T, brow0);
        } else {
            if (!lead) dumpS(A_Q, acc);
            __syncthreads();
        }
        if (lead) finishS(A_Q, acc, cQ, 1, t);
        if (t == 0) loadB(wsum16);
        __syncthreads();
    }

    // ---- wait own group fully done ----
    if (wv == 0) {
        const unsigned* p0 = gflags + (l & 31) * 128 + (l >> 5) * 32;
        while (true) {
            unsigned a = load4_cp(p0);
            unsigned b = load4_cp(p0 + 64);
            if (__all((a >= (unsigned)Ts) & (b >= (unsigned)Ts))) break;
            __builtin_amdgcn_s_sleep(1);
        }
    }
    __syncthreads();

    // ---------------- fused output projection (group-local rows) ----------------
    {
        const int idx  = wgi * 8 + wv;          // 0..255
        const int t_   = idx >> 1;              // 0..127
        const int bb16 = brow0 + (idx & 1) * 16;
        const int row  = bb16 + lr;
        const char* ab = seqc + (size_t)t_ * SEQ_T + (size_t)row * 64 + lk * 16;

        f32x4 oacc[8];
        #pragma unroll
        for (int ni = 0; ni < 8; ++ni) oacc[ni] = f32x4{0.f,0.f,0.f,0.f};

        #pragma unroll 2
        for (int k0 = 0; k0 < Hd; k0 += 32) {
            half8 a = *(const half8*)(ab + (size_t)k0 * 512);  // jb = k0/32 blocks
            #pragma unroll
            for (int ni = 0; ni < 8; ++ni) {
                half8 bf = *(const half8*)(wout16 + (size_t)(ni * 16 + lr) * Hd + lk * 8 + k0);
                oacc[ni] = __builtin_amdgcn_mfma_f32_16x16x32_f16(a, bf, oacc[ni], 0,0,0);
            }
        }
        #pragma unroll
        for (int ni = 0; ni < 8; ++ni) {
            const int d  = ni * 16 + lr;
            const float bo = bout[d];
            #pragma unroll
            for (int r = 0; r < 4; ++r) {
                const int b = bb16 + lk * 4 + r;
                out[(size_t)b * (Ts * DOUT) + t_ * DOUT + d] = oacc[ni][r] + bo;
            }
        }
    }
}

extern "C" void kernel_launch(void* const* d_in, const int* in_sizes, int n_in,
                              void* d_out, int out_size, void* d_ws, size_t ws_size,
                              hipStream_t stream) {
    const float* x    = (const float*)d_in[0];
    const float* Wih  = (const float*)d_in[1];
    const float* Whh  = (const float*)d_in[2];
    const float* bih  = (const float*)d_in[3];
    const float* bhh  = (const float*)d_in[4];
    const float* Wout = (const float*)d_in[5];
    const float* bout = (const float*)d_in[6];

    if (ws_size < WS_NEED) return;

    char* ws = (char*)d_ws;
    _Float16* wsum16 = (_Float16*)(ws + OFF_WSUM);
    _Float16* wih16  = (_Float16*)(ws + OFF_WIH);
    _Float16* wout16 = (_Float16*)(ws + OFF_WOUT);
    _Float16* x16    = (_Float16*)(ws + OFF_X);
    float*    bsum   = (float*)(ws + OFF_BSUM);
    unsigned* bar    = (unsigned*)(ws + OFF_BAR);
    _Float16* seq    = (_Float16*)(ws + OFF_SEQ);
    float*    outp   = (float*)d_out;

    hipLaunchKernelGGL(prep_kernel, dim3(1024), dim3(256), 0, stream,
                       Wih, Whh, bih, bhh, x, Wout,
                       wsum16, wih16, wout16, x16, bsum, bar);

    void* args[] = { &wsum16, &wih16, &wout16, &x16, &bsum,
                     (void*)&bout, &seq, &outp, &bar };
    hipLaunchCooperativeKernel((void*)lstm_kernel, dim3(NWG), dim3(NTHR),
                               args, 0, stream);
}